// Round 12
// baseline (2719.794 us; speedup 1.0000x reference)
//
#include <hip/hip_runtime.h>

#define Bdim 512
#define Tt   256
#define Ii   128
#define Hh   512
#define BM   16     // batch rows per group
#define NGRP 32
#define NSL  8      // column slices (WGs) per group

typedef __attribute__((ext_vector_type(4))) float f32x4;
typedef __attribute__((ext_vector_type(4))) unsigned u32x4;
typedef __attribute__((ext_vector_type(8))) short short8;
typedef unsigned long long u64;
typedef unsigned u32;

__device__ __forceinline__ unsigned short f2bf(float f) {
    u32 u = __builtin_bit_cast(u32, f);
    u += 0x7fffu + ((u >> 16) & 1u);   // round-to-nearest-even
    return (unsigned short)(u >> 16);
}

__device__ __forceinline__ short8 pack_bf8(f32x4 lo, f32x4 hi) {
    short8 r;
    r[0] = (short)f2bf(lo[0]); r[1] = (short)f2bf(lo[1]);
    r[2] = (short)f2bf(lo[2]); r[3] = (short)f2bf(lo[3]);
    r[4] = (short)f2bf(hi[0]); r[5] = (short)f2bf(hi[1]);
    r[6] = (short)f2bf(hi[2]); r[7] = (short)f2bf(hi[3]);
    return r;
}

// weight A-fragment: lane holds W[row][k..k+8), K-order: h-cols then x-cols
__device__ __forceinline__ short8 load_wfrag(const float* __restrict__ Whh,
                                             const float* __restrict__ Wih,
                                             int row, int k) {
    const float* p = (k < Hh) ? (Whh + row * Hh + k) : (Wih + row * Ii + (k - Hh));
    f32x4 lo = *(const f32x4*)p;
    f32x4 hi = *(const f32x4*)(p + 4);
    return pack_bf8(lo, hi);
}

__device__ __forceinline__ float sigm(float v)  { return 1.f / (1.f + __expf(-v)); }
__device__ __forceinline__ float tanhf_(float v){ return 1.f - 2.f / (__expf(2.f * v) + 1.f); }

// PROVEN exchange primitives (agent scope / LLC, rounds 4-11)
__device__ __forceinline__ u64 aload(const u64* p) {
    return __hip_atomic_load(p, __ATOMIC_RELAXED, __HIP_MEMORY_SCOPE_AGENT);
}
__device__ __forceinline__ void astore(u64* p, u64 v) {
    __hip_atomic_store(p, v, __ATOMIC_RELAXED, __HIP_MEMORY_SCOPE_AGENT);
}
__device__ __forceinline__ int aload32(const int* p) {
    return __hip_atomic_load(p, __ATOMIC_RELAXED, __HIP_MEMORY_SCOPE_AGENT);
}
__device__ __forceinline__ void astore32(int* p, int v) {
    __hip_atomic_store(p, v, __ATOMIC_RELAXED, __HIP_MEMORY_SCOPE_AGENT);
}

#define MFMA16(A, B, C) __builtin_amdgcn_mfma_f32_16x16x32_bf16((A), (B), (C), 0, 0, 0)

// Exchange layout (u64 units), round-10 verified:
//   F[(buf*NGRP+g)*4096 + kt*256 + l*4 + j]   (j = 0..3)
// = consumer-lane l's quantum j of k-tile kt:
//   { lo32 = bf16(h[batch=l&15][kt*32+(l>>4)*8+2j  ])<<16 | tag,
//     hi32 = bf16(...                          +2j+1])<<16 | tag }
// 8B store atomicity (proven) => lo-word tag validates the quantum.
// Flags (round-11 verified): per producer wave, 32 per group; flag posted
// WITHOUT a drain — tags are the correctness backstop for in-flight data.

// issue the 16 loads of quarter QI (k-tiles 4QI..4QI+3)
#define LOADQ(Q, QI)                                                            \
    _Pragma("unroll")                                                           \
    for (int s = 0; s < 16; ++s)                                                \
        Q[s] = aload(Frb + ((QI) * 4 + (s >> 2)) * 256 + (s & 3));

// pack + tag-validate (rare bounded reload) + 12 MFMAs of quarter QI
#define PVQ(Q, QI)                                                              \
{                                                                               \
    u32x4 pk0, pk1, pk2, pk3;                                                   \
    for (;;) {                                                                  \
        u32 bad = 0;                                                            \
        _Pragma("unroll")                                                       \
        for (int j = 0; j < 4; ++j) {                                           \
            u64 q_ = Q[j];                                                      \
            bad |= ((u32)q_ ^ wtag) & 0xffffu;                                  \
            pk0[j] = ((u32)q_ >> 16) | ((u32)(q_ >> 32) & 0xffff0000u);         \
        }                                                                       \
        _Pragma("unroll")                                                       \
        for (int j = 0; j < 4; ++j) {                                           \
            u64 q_ = Q[4 + j];                                                  \
            bad |= ((u32)q_ ^ wtag) & 0xffffu;                                  \
            pk1[j] = ((u32)q_ >> 16) | ((u32)(q_ >> 32) & 0xffff0000u);         \
        }                                                                       \
        _Pragma("unroll")                                                       \
        for (int j = 0; j < 4; ++j) {                                           \
            u64 q_ = Q[8 + j];                                                  \
            bad |= ((u32)q_ ^ wtag) & 0xffffu;                                  \
            pk2[j] = ((u32)q_ >> 16) | ((u32)(q_ >> 32) & 0xffff0000u);         \
        }                                                                       \
        _Pragma("unroll")                                                       \
        for (int j = 0; j < 4; ++j) {                                           \
            u64 q_ = Q[12 + j];                                                 \
            bad |= ((u32)q_ ^ wtag) & 0xffffu;                                  \
            pk3[j] = ((u32)q_ >> 16) | ((u32)(q_ >> 32) & 0xffff0000u);         \
        }                                                                       \
        if (!__any(bad != 0) || --budget < 0) break;                            \
        LOADQ(Q, QI)                                                            \
    }                                                                           \
    {                                                                           \
        short8 b0_ = __builtin_bit_cast(short8, pk0);                           \
        short8 b1_ = __builtin_bit_cast(short8, pk1);                           \
        short8 b2_ = __builtin_bit_cast(short8, pk2);                           \
        short8 b3_ = __builtin_bit_cast(short8, pk3);                           \
        int kt = (QI) * 4;                                                      \
        accR  = MFMA16(wR[kt],     b0_, accR);                                  \
        accZ  = MFMA16(wZ[kt],     b0_, accZ);                                  \
        accNH = MFMA16(wN[kt],     b0_, accNH);                                 \
        accR  = MFMA16(wR[kt + 1], b1_, accR);                                  \
        accZ  = MFMA16(wZ[kt + 1], b1_, accZ);                                  \
        accNH = MFMA16(wN[kt + 1], b1_, accNH);                                 \
        accR  = MFMA16(wR[kt + 2], b2_, accR);                                  \
        accZ  = MFMA16(wZ[kt + 2], b2_, accZ);                                  \
        accNH = MFMA16(wN[kt + 2], b2_, accNH);                                 \
        accR  = MFMA16(wR[kt + 3], b3_, accR);                                  \
        accZ  = MFMA16(wZ[kt + 3], b3_, accZ);                                  \
        accNH = MFMA16(wN[kt + 3], b3_, accNH);                                 \
    }                                                                           \
}

// bounded poll of half H's 16 wave-flags (round-11 verified)
#define POLLH(H, WT)                                                            \
    for (;;) {                                                                  \
        int f_ = aload32(gflags + (H) * 16 + (lane & 15));                      \
        if (__all(f_ >= (WT)) || --budget < 0) break;                           \
    }                                                                           \
    __builtin_amdgcn_sched_barrier(0);

__global__ __launch_bounds__(256, 1)
void gru_persist(const float* __restrict__ x,   const float* __restrict__ Wih,
                 const float* __restrict__ Whh, const float* __restrict__ bih,
                 const float* __restrict__ bhh, const float* __restrict__ Wlin,
                 const float* __restrict__ blin, float* __restrict__ out,
                 u64* __restrict__ F, int* __restrict__ flags)
{
    const int wg   = blockIdx.x;
    const int tid  = threadIdx.x;
    const int lane = tid & 63;
    const int w    = tid >> 6;          // wave 0..3
    // Keep a group's 8 slices on nearby CUs (perf heuristic only; correctness
    // does not depend on placement — exchange is agent-scope at the LLC).
    const int xcd8 = wg & 7, lg = (wg >> 3) & 3, sl = wg >> 5;
    const int gi  = xcd8 * 4 + lg;      // group 0..31
    const int b0  = gi * BM;
    const int jw  = sl * 64 + w * 16;   // this wave's 16 gate/h columns
    const int l15 = lane & 15;          // batch row within group (D col)
    const int cg  = lane >> 4;          // 4-col chunk / k-half selector
    const int kg8 = cg * 8;
    const int colg = jw + l15;          // gate row this lane holds weights for
    // producer slot math (round-10 verified)
    const int wc   = 4 * w + cg;
    const int kt_w = sl * 2 + (wc >> 3);
    const int fl   = l15 + 16 * ((wc & 7) >> 1);
    const int j0   = 2 * (cg & 1);

    // biases for lane's 4 gate columns jw + cg*4 + i
    f32x4 brv, bzv, bxnv, bhnv;
#pragma unroll
    for (int i = 0; i < 4; ++i) {
        int c = jw + cg * 4 + i;
        brv[i]  = bih[c] + bhh[c];
        bzv[i]  = bih[Hh + c] + bhh[Hh + c];
        bxnv[i] = bih[2 * Hh + c];
        bhnv[i] = bhh[2 * Hh + c];
    }

    // ---- weight A-fragments, resident for the whole kernel ----
    short8 wR[20], wZ[20], wN[20];
#pragma unroll
    for (int kt = 0; kt < 20; ++kt) {
        int k = kt * 32 + kg8;
        wR[kt] = load_wfrag(Whh, Wih, colg, k);
        wZ[kt] = load_wfrag(Whh, Wih, Hh + colg, k);
        wN[kt] = load_wfrag(Whh, Wih, 2 * Hh + colg, k);
    }

    int* gflags = flags + gi * 32;
    f32x4 hreg = {0.f, 0.f, 0.f, 0.f};  // own (batch=l15, cols jw+cg*4..+4) fp32 carry
    int budget = 1 << 22;               // global spin budget: bug => fast wrong
                                        // answer, never a hang

    // x for t=0 (f32 regs, packed transiently at step head)
    f32x4 xa[4], xb[4];
    {
        const float* xp = x + ((size_t)(b0 + l15) * Tt + 0) * Ii + kg8;
#pragma unroll
        for (int kt = 0; kt < 4; ++kt) {
            xa[kt] = *(const f32x4*)(xp + kt * 32);
            xb[kt] = *(const f32x4*)(xp + kt * 32 + 4);
        }
    }

#pragma unroll 1
    for (int t = 0; t < Tt; ++t) {
        const int wb = t & 1, rb = wb ^ 1;

        // ---- probe issued FIRST: its LLC round trip hides under the x head ----
        int probe = 0x7fffffff;
        if (t > 0) probe = aload32(gflags + (lane & 31));

        f32x4 accR = {0,0,0,0}, accZ = {0,0,0,0}, accNH = {0,0,0,0}, accNX = {0,0,0,0};

        // ---- x-part MFMAs (A=W, B=x^T); pack transient ----
#pragma unroll
        for (int kt = 0; kt < 4; ++kt) {
            short8 bxk = pack_bf8(xa[kt], xb[kt]);
            accR  = MFMA16(wR[16 + kt], bxk, accR);
            accZ  = MFMA16(wZ[16 + kt], bxk, accZ);
            accNX = MFMA16(wN[16 + kt], bxk, accNX);
        }

        // x prefetch for t+1: in flight through the whole h-phase
        if (t + 1 < Tt) {
            const float* xp = x + ((size_t)(b0 + l15) * Tt + (t + 1)) * Ii + kg8;
#pragma unroll
            for (int kt = 0; kt < 4; ++kt) {
                xa[kt] = *(const f32x4*)(xp + kt * 32);
                xb[kt] = *(const f32x4*)(xp + kt * 32 + 4);
            }
        }

        if (t > 0) {
            const int wt = t - 1;
            const u32 wtag = (u32)wt;
            const u64* Frb = F + (size_t)(rb * NGRP + gi) * 4096 + lane * 4;
            u64 qta[16], qtb[16];
            if (__all(probe >= wt)) {
                // FAST: everything ready at probe — no polls at all
                LOADQ(qta, 0) LOADQ(qtb, 1)
                PVQ(qta, 0)   LOADQ(qta, 2)
                PVQ(qtb, 1)   LOADQ(qtb, 3)
                PVQ(qta, 2)   PVQ(qtb, 3)
            } else {
                int f0 = aload32(gflags + (lane & 15));
                if (__all(f0 >= wt)) {
                    LOADQ(qta, 0) LOADQ(qtb, 1)
                    POLLH(1, wt)
                    PVQ(qta, 0)   LOADQ(qta, 2)
                    PVQ(qtb, 1)   LOADQ(qtb, 3)
                    PVQ(qta, 2)   PVQ(qtb, 3)
                } else {
                    int f1 = aload32(gflags + 16 + (lane & 15));
                    if (__all(f1 >= wt)) {
                        LOADQ(qta, 2) LOADQ(qtb, 3)
                        POLLH(0, wt)
                        PVQ(qta, 2)   LOADQ(qta, 0)
                        PVQ(qtb, 3)   LOADQ(qtb, 1)
                        PVQ(qta, 0)   PVQ(qtb, 1)
                    } else {
                        POLLH(0, wt)
                        LOADQ(qta, 0) LOADQ(qtb, 1)
                        POLLH(1, wt)
                        PVQ(qta, 0)   LOADQ(qta, 2)
                        PVQ(qtb, 1)   LOADQ(qtb, 3)
                        PVQ(qta, 2)   PVQ(qtb, 3)
                    }
                }
            }
        }

        // ---- gates + state update (lane: batch=l15, cols jw+cg*4 .. +4) ----
        f32x4 hnew;
#pragma unroll
        for (int i = 0; i < 4; ++i) {
            float r = sigm(accR[i] + brv[i]);
            float z = sigm(accZ[i] + bzv[i]);
            float n = tanhf_(accNX[i] + bxnv[i] + r * (accNH[i] + bhnv[i]));
            hnew[i] = (1.f - z) * n + z * hreg[i];
        }
        hreg = hnew;

        // ---- publish: 2 tagged u64 stores + flag, NO drain (tags backstop
        //      in-flight data; flag is only the wait-gate) ----
        {
            u32 tg = (u32)t;
            u64 v0 = ((u64)(((u32)f2bf(hnew[0]) << 16) | tg))
                   | ((u64)(((u32)f2bf(hnew[1]) << 16) | tg) << 32);
            u64 v1 = ((u64)(((u32)f2bf(hnew[2]) << 16) | tg))
                   | ((u64)(((u32)f2bf(hnew[3]) << 16) | tg) << 32);
            u64* Fw = F + (size_t)(wb * NGRP + gi) * 4096 + (size_t)kt_w * 256 + fl * 4 + j0;
            astore(Fw,     v0);
            astore(Fw + 1, v1);
        }
        if (lane == 0)
            astore32(gflags + sl * 4 + w, t);
        __builtin_amdgcn_sched_barrier(0);   // publish precedes next-step work
    }

    // ---- final linear: wave 0 of slice-0 WG computes out[b0..b0+15] ----
    if (sl == 0 && w == 0) {
        for (;;) {
            int f = aload32(gflags + (lane & 31));
            if (__all(f >= Tt - 1) || --budget < 0) break;
        }
        __builtin_amdgcn_sched_barrier(0);
        // final state is in buffer (Tt-1)&1 = 1; tag-validated reads (R10)
        const u64* Frl = F + (size_t)(1 * NGRP + gi) * 4096 + lane * 4;
        const u32 wtag = (u32)(Tt - 1);
        float sum = 0.f;
#pragma unroll 1
        for (int kt = 0; kt < 16; ++kt) {
            u64 q[4];
            for (;;) {
#pragma unroll
                for (int j = 0; j < 4; ++j) q[j] = aload(Frl + kt * 256 + j);
                u32 bad = 0;
#pragma unroll
                for (int j = 0; j < 4; ++j) bad |= ((u32)q[j] ^ wtag) & 0xffffu;
                if (!__any(bad != 0) || --budget < 0) break;
            }
            int kbase = kt * 32 + kg8;
#pragma unroll
            for (int j = 0; j < 4; ++j) {
                float f0 = __builtin_bit_cast(float, (u32)q[j] & 0xffff0000u);
                float f1 = __builtin_bit_cast(float, (u32)(q[j] >> 32) & 0xffff0000u);
                sum += f0 * Wlin[kbase + 2 * j] + f1 * Wlin[kbase + 2 * j + 1];
            }
        }
        sum += __shfl_xor(sum, 16);
        sum += __shfl_xor(sum, 32);
        if (lane < 16) out[b0 + l15] = sum + blin[0];
    }
}

extern "C" void kernel_launch(void* const* d_in, const int* in_sizes, int n_in,
                              void* d_out, int out_size, void* d_ws, size_t ws_size,
                              hipStream_t stream) {
    const float* x    = (const float*)d_in[0];
    const float* Wih  = (const float*)d_in[1];
    const float* Whh  = (const float*)d_in[2];
    const float* bih  = (const float*)d_in[3];
    const float* bhh  = (const float*)d_in[4];
    const float* Wlin = (const float*)d_in[5];
    const float* blin = (const float*)d_in[6];
    float* out  = (float*)d_out;

    u64* F = (u64*)d_ws;   // 2 bufs * 32 groups * 4096 u64 = 2 MB (tagged)
    int* flags = (int*)((char*)d_ws + 2ull * NGRP * 4096 * sizeof(u64));

    // one memset covers tags (0xFFFF matches no step: kills cross-replay
    // aliasing, R10-proven) AND flags (-1)
    const size_t fbytes = 2ull * NGRP * 4096 * sizeof(u64) + NGRP * 32 * sizeof(int);
    hipMemsetAsync(F, 0xFF, fbytes, stream);
    gru_persist<<<256, 256, 0, stream>>>(x, Wih, Whh, bih, bhh, Wlin, blin, out,
                                         F, flags);
}